// Round 14
// baseline (159.882 us; speedup 1.0000x reference)
//
#include <hip/hip_runtime.h>
#include <stdint.h>

typedef unsigned short u16;
typedef __attribute__((ext_vector_type(8))) short short8;
typedef __attribute__((ext_vector_type(4))) short s16x4;
typedef __attribute__((ext_vector_type(4))) float f32x4;
typedef __attribute__((ext_vector_type(2))) unsigned uint2v;

#define MFMA16(a, b, c) __builtin_amdgcn_mfma_f32_16x16x32_bf16(a, b, c, 0, 0, 0)

// PV uses K=16 bf16 MFMA: B-operand k-layout (kg*4+i) matches swapped-QK P layout.
#if __has_builtin(__builtin_amdgcn_mfma_f32_16x16x16bf16_1k)
__device__ __forceinline__ f32x4 pv_mfma(s16x4 a, s16x4 b, f32x4 c) {
  return __builtin_amdgcn_mfma_f32_16x16x16bf16_1k(a, b, c, 0, 0, 0);
}
#else
__device__ __forceinline__ f32x4 pv_mfma(s16x4 a, s16x4 b, f32x4 c) {
  asm volatile("v_mfma_f32_16x16x16_bf16 %0, %1, %2, %0" : "+v"(c) : "v"(a), "v"(b));
  return c;
}
#endif

__device__ __forceinline__ void async16(void* lds, const void* g) {
  __builtin_amdgcn_global_load_lds(
      (const __attribute__((address_space(1))) void*)g,
      (__attribute__((address_space(3))) void*)lds, 16, 0, 0);
}

__device__ __forceinline__ u16 f2bf(float f) {
  unsigned u = __float_as_uint(f);
  u += 0x7FFF + ((u >> 16) & 1);
  return (u16)(u >> 16);
}

__device__ __forceinline__ unsigned cvtpk(float lo, float hi) {
  unsigned r;
  asm("v_cvt_pk_bf16_f32 %0, %1, %2" : "=v"(r) : "v"(lo), "v"(hi));
  return r;
}

// Q is pre-scaled by 1/sqrt(dh) * log2(e) so softmax runs in exp2 domain.
#define QSCALE 0.18033688011112042f
// Mask sentinel: exp2f(MASKV) == 0 exactly; no arithmetic on it can overflow.
#define MASKV -30000.0f

// ---------------- fp32 -> bf16 conversion ----------------
__global__ void convert_x(const float* __restrict__ src, u16* __restrict__ dst) {
  int i = blockIdx.x * 256 + threadIdx.x;
  float4 v = ((const float4*)src)[i];
  unsigned lo = (unsigned)f2bf(v.x) | ((unsigned)f2bf(v.y) << 16);
  unsigned hi = (unsigned)f2bf(v.z) | ((unsigned)f2bf(v.w) << 16);
  ((uint2*)dst)[i] = make_uint2(lo, hi);
}

__global__ void convert_w(const float* __restrict__ wq, const float* __restrict__ wk,
                          const float* __restrict__ wv, const float* __restrict__ wo,
                          u16* __restrict__ wqkv, u16* __restrict__ wob) {
  int i = blockIdx.x * 256 + threadIdx.x;   // [0, 589824)
  int wsel = i / 147456;
  int r = i - wsel * 147456;
  const float* s = (wsel == 0) ? wq : (wsel == 1) ? wk : (wsel == 2) ? wv : wo;
  float4 v = ((const float4*)s)[r];
  unsigned lo = (unsigned)f2bf(v.x) | ((unsigned)f2bf(v.y) << 16);
  unsigned hi = (unsigned)f2bf(v.z) | ((unsigned)f2bf(v.w) << 16);
  uint2 w = make_uint2(lo, hi);
  if (wsel < 3) ((uint2*)wqkv)[wsel * 147456 + r] = w;
  else ((uint2*)wob)[r] = w;
}

// ---------------- GEMM: C[m,n] = sum_k A[m,k] * Bw[n,k]  (both bf16, K=768) ----
// 128x128 tile, BK=32, double-buffered LDS with global_load_lds prefetch.
// ORIENTATION per output layout (R13 fix: 2x write amplification + 64 scalar
// stores/thread in the scatter epilogues):
//  - Q/K blocks and MODE 1: SWAPPED mfma(W,X) -> lane holds 4 consecutive d/c
//    (row=kg*4+i ↦ hc/c, col=arow ↦ s) -> 8B bf16-pair / 16B float4 stores.
//  - V blocks: normal mfma(X,W) -> lane holds 4 consecutive s -> 8B stores
//    into V^T (unchanged). Both fragments load identically, so swapping
//    operand order is layout-consistent (same trick as attn's swapped QK^T).
template <int MODE>
__global__ __launch_bounds__(256) void gemm_bt(const u16* __restrict__ A,
                                               const u16* __restrict__ Bw,
                                               u16* __restrict__ Qb, u16* __restrict__ Kb,
                                               u16* __restrict__ Vb, float* __restrict__ Out) {
  __shared__ __align__(16) u16 As[2][128 * 32];
  __shared__ __align__(16) u16 Bs[2][128 * 32];
  const int bm = blockIdx.x & 63;   // 64 M-tiles
  const int bn = blockIdx.x >> 6;
  const int tid = threadIdx.x;
  const int wave = tid >> 6, lane = tid & 63;
  const int arow = lane & 15, kg = lane >> 4;
  const int wr = wave >> 1, wc = wave & 1;
  const int which = (MODE == 0) ? (bn / 6) : 0;      // 0=Q 1=K 2=V (block-uniform)
  const bool swp = (MODE == 1) || (which < 2);       // swapped-orientation blocks

  const int o = tid * 16;
  const int rowS = o >> 6;     // 64B rows (BK=32 bf16)
  const int cbS = o & 63;
  const char* gA0 = (const char*)A + (size_t)(bm * 128 + rowS) * 1536 + cbS;
  const char* gA1 = gA0 + (size_t)64 * 1536;
  const char* gB0 = (const char*)Bw + (size_t)(bn * 128 + rowS) * 1536 + cbS;
  const char* gB1 = gB0 + (size_t)64 * 1536;
  const int ldsw = wave * 1024;

  f32x4 acc[4][4];
#pragma unroll
  for (int m = 0; m < 4; ++m)
#pragma unroll
    for (int n = 0; n < 4; ++n) acc[m][n] = (f32x4)(0.0f);

  auto stage = [&](int buf) {
    async16((char*)As + buf * 8192 + ldsw,        gA0);
    async16((char*)As + buf * 8192 + ldsw + 4096, gA1);
    async16((char*)Bs + buf * 8192 + ldsw,        gB0);
    async16((char*)Bs + buf * 8192 + ldsw + 4096, gB1);
    gA0 += 64; gA1 += 64; gB0 += 64; gB1 += 64;
  };

  stage(0);
  asm volatile("s_waitcnt vmcnt(0)" ::: "memory");
  __builtin_amdgcn_s_barrier();

  int cur = 0;
  for (int kk = 0; kk < 24; ++kk) {
    if (kk + 1 < 24) stage(cur ^ 1);   // prefetch next K-step (hides under compute)

    const char* Ac = (const char*)As + cur * 8192;
    const char* Bc = (const char*)Bs + cur * 8192;
    short8 Xf[4], Wf[4];
#pragma unroll
    for (int m = 0; m < 4; ++m)
      Xf[m] = *(const short8*)(Ac + (wr * 64 + m * 16 + arow) * 64 + kg * 16);
#pragma unroll
    for (int n = 0; n < 4; ++n)
      Wf[n] = *(const short8*)(Bc + (wc * 64 + n * 16 + arow) * 64 + kg * 16);
    if (swp) {
#pragma unroll
      for (int m = 0; m < 4; ++m)
#pragma unroll
        for (int n = 0; n < 4; ++n) acc[m][n] = MFMA16(Wf[n], Xf[m], acc[m][n]);
    } else {
#pragma unroll
      for (int m = 0; m < 4; ++m)
#pragma unroll
        for (int n = 0; n < 4; ++n) acc[m][n] = MFMA16(Xf[m], Wf[n], acc[m][n]);
    }

    asm volatile("s_waitcnt vmcnt(0)" ::: "memory");
    __builtin_amdgcn_s_barrier();
    cur ^= 1;
  }

  if (MODE == 0) {
    const int b = bm >> 4;                         // batch (block-uniform)
    const int cbase = bn * 128 - which * 768 + wc * 64;
    if (which == 2) {
      // V (normal orientation): lane holds 4 consecutive s -> 8B stores to V^T
      const int sb = (bm & 15) * 128 + wr * 64 + kg * 4;  // + m*16 + i -> s
#pragma unroll
      for (int n = 0; n < 4; ++n) {
        int hc = cbase + n * 16 + arow;
        size_t rowb = ((size_t)(b * 12 + (hc >> 6)) * 64 + (hc & 63)) * 2048;
#pragma unroll
        for (int m = 0; m < 4; ++m) {
          uint2v w;
          w.x = cvtpk(acc[m][n][0], acc[m][n][1]);
          w.y = cvtpk(acc[m][n][2], acc[m][n][3]);
          *(uint2v*)(Vb + rowb + sb + m * 16) = w;
        }
      }
    } else {
      // Q/K (swapped orientation): lane holds 4 consecutive d -> 8B stores
      u16* const dst = which ? Kb : Qb;
      const float sc = which ? 1.0f : QSCALE;
      const int s0 = (bm & 15) * 128 + wr * 64 + arow;    // + m*16 -> s
#pragma unroll
      for (int n = 0; n < 4; ++n) {
        int hc0 = cbase + n * 16 + kg * 4;                // 4 consecutive d via i
        size_t hb = ((size_t)(b * 12 + (hc0 >> 6)) * 2048) * 64 + (hc0 & 63);
#pragma unroll
        for (int m = 0; m < 4; ++m) {
          uint2v w;
          w.x = cvtpk(acc[m][n][0] * sc, acc[m][n][1] * sc);
          w.y = cvtpk(acc[m][n][2] * sc, acc[m][n][3] * sc);
          *(uint2v*)(dst + hb + (size_t)(s0 + m * 16) * 64) = w;
        }
      }
    }
  } else {
    // MODE 1 (swapped orientation): lane holds 4 consecutive c -> float4 stores
    const int rbase = bm * 128 + wr * 64 + arow;          // + m*16 -> row
    const int c0 = bn * 128 + wc * 64 + kg * 4;           // + n*16 -> col
#pragma unroll
    for (int m = 0; m < 4; ++m)
#pragma unroll
      for (int n = 0; n < 4; ++n) {
        float4 st = make_float4(acc[m][n][0], acc[m][n][1], acc[m][n][2], acc[m][n][3]);
        *(float4*)(Out + (size_t)(rbase + m * 16) * 768 + c0 + n * 16) = st;
      }
  }
}

// ---------------- causal flash attention (swapped QK^T, ADJACENT pairing, ----
// ---------------- STATIC softmax) — byte-identical to the R13 passing build --
__global__ __launch_bounds__(512, 4) void attn_kernel(const u16* __restrict__ Qb,
                                                      const u16* __restrict__ Kb,
                                                      const u16* __restrict__ Vb,  // [bh][64][2048]
                                                      u16* __restrict__ AOb) {
  __shared__ __align__(16) u16 Ks[2][64 * 64];   // K tiles, XOR-swizzled 128B rows
  __shared__ __align__(16) u16 Vt[2][64 * 64];   // V^T tiles [d][k], XOR-swizzled

  const int bid = blockIdx.x;
  const int t = 15 - (bid / 48);     // pair index, heavy-first (t=15: 32 steps)
  const int bh = bid % 48;
  const int tid = threadIdx.x, wave = tid >> 6, lane = tid & 63;
  const int wgrp = wave >> 2, wq = wave & 3;
  const int arow = lane & 15, kg = lane >> 4;
  const int qt = wgrp ? (2 * t) : (2 * t + 1);   // group 0: odd (long); group 1: even
  const size_t hbase = (size_t)bh * (2048 * 64);
  const u16* Qh = Qb + hbase;
  const int q0 = qt * 64 + wq * 16;

  short8 qf[2];
#pragma unroll
  for (int ks = 0; ks < 2; ++ks)
    qf[ks] = *(const short8*)(Qh + (size_t)(q0 + arow) * 64 + ks * 32 + kg * 8);

  f32x4 o_acc[4];
#pragma unroll
  for (int n = 0; n < 4; ++n) o_acc[n] = (f32x4)(0.0f);
  float lsum = 0.0f;   // lane-local; reduced across kg groups in the epilogue

  const int o0 = tid * 16;                  // [0, 8192)
  const int r0 = o0 >> 7, cb0 = o0 & 127;   // row 0..63, byte-in-row
  const int sw0 = cb0 ^ (((r0 ^ (r0 >> 3)) & 7) << 4);
  char* const KsB = (char*)Ks;
  char* const VtB = (char*)Vt;
  const int ldsw = wave << 10;              // wave-uniform base offset

  const char* gK = (const char*)(Kb + hbase) + r0 * 128 + sw0;
  const char* gV = (const char*)(Vb + hbase) + (size_t)r0 * 4096 + sw0;

  const int nt = 2 * t + 2;   // k-steps for this pair (long tile's range)

  auto stage = [&](int buf) {
    async16(KsB + buf * 8192 + ldsw, gK);
    async16(VtB + buf * 8192 + ldsw, gV);
    gK += 8192;   // next K tile: 64 rows * 128B
    gV += 128;    // next V^T tile: 64 columns * 2B
  };

  const int rel = wq * 16 + arow - kg * 4;   // diag mask helper (q - kbase - kg*4)

  stage(0);
  __syncthreads();

  int cur = 0;
  for (int kt = 0; kt < nt; ++kt) {
    if (kt + 1 < nt) stage(cur ^ 1);   // prefetch next tile; lands during compute

    if (kt <= qt) {                    // wave-uniform; group 1 idles ONLY at kt=nt-1
      const char* Kc = KsB + cur * 8192;
      const char* Vc = VtB + cur * 8192;

      f32x4 s_acc[4];
#pragma unroll
      for (int cg = 0; cg < 4; ++cg) s_acc[cg] = (f32x4)(0.0f);
#pragma unroll
      for (int cg = 0; cg < 4; ++cg) {
        int krow = cg * 16 + arow;
        int fsw = ((krow ^ (krow >> 3)) & 7) << 4;
#pragma unroll
        for (int ks = 0; ks < 2; ++ks) {
          short8 kf = *(const short8*)(Kc + (krow << 7) + ((ks * 64 + kg * 16) ^ fsw));
          s_acc[cg] = MFMA16(kf, qf[ks], s_acc[cg]);
        }
      }

      if (kt == qt) {
#pragma unroll
        for (int cg = 0; cg < 4; ++cg)
#pragma unroll
          for (int i = 0; i < 4; ++i)
            s_acc[cg][i] = (cg * 16 + i > rel) ? MASKV : s_acc[cg][i];
      }

      // static softmax: P = exp2(s) direct; lane-local l accumulation
      s16x4 pb[4];
#pragma unroll
      for (int cg = 0; cg < 4; ++cg) {
        float e0 = exp2f(s_acc[cg][0]);
        float e1 = exp2f(s_acc[cg][1]);
        float e2 = exp2f(s_acc[cg][2]);
        float e3 = exp2f(s_acc[cg][3]);
        lsum += e0 + e1 + e2 + e3;
        uint2v w;
        w.x = cvtpk(e0, e1);
        w.y = cvtpk(e2, e3);
        pb[cg] = __builtin_bit_cast(s16x4, w);
      }

#pragma unroll
      for (int n = 0; n < 4; ++n) {
        int vrow = n * 16 + arow;
        int f2 = ((vrow ^ (vrow >> 3)) & 7) << 4;
        const char* vb0 = Vc + (vrow << 7);
#pragma unroll
        for (int cg = 0; cg < 4; ++cg) {
          s16x4 va = *(const s16x4*)(vb0 + ((cg * 32 + kg * 8) ^ f2));
          o_acc[n] = pv_mfma(va, pb[cg], o_acc[n]);
        }
      }
    }

    __syncthreads();   // drains vmcnt+lgkm; next tile ready, buffer reads done
    cur ^= 1;
  }

  lsum += __shfl_xor(lsum, 16);
  lsum += __shfl_xor(lsum, 32);
  const int b = bh / 12, h = bh - b * 12;
  float rinv = 1.0f / lsum;   // lsum > 0: diagonal p = exp2(finite) > 0
  size_t obase = ((size_t)b * 2048 + q0 + arow) * 768 + h * 64 + kg * 4;
#pragma unroll
  for (int n = 0; n < 4; ++n) {
#pragma unroll
    for (int t2 = 0; t2 < 2; ++t2) {
      unsigned w = cvtpk(o_acc[n][2 * t2] * rinv, o_acc[n][2 * t2 + 1] * rinv);
      *(unsigned*)(&AOb[obase + n * 16 + 2 * t2]) = w;
    }
  }
}

// ---------------- launch ----------------
extern "C" void kernel_launch(void* const* d_in, const int* in_sizes, int n_in,
                              void* d_out, int out_size, void* d_ws, size_t ws_size,
                              hipStream_t stream) {
  const float* x = (const float*)d_in[0];
  const float* wq = (const float*)d_in[1];
  const float* wk = (const float*)d_in[2];
  const float* wv = (const float*)d_in[3];
  const float* wo = (const float*)d_in[4];
  float* out = (float*)d_out;

  char* ws = (char*)d_ws;
  u16* xb   = (u16*)(ws);                 // [8192][768]
  u16* wqkv = (u16*)(ws + 12582912);      // [2304][768] rows: wq, wk, wv
  u16* wob  = (u16*)(ws + 16121856);      // [768][768]
  u16* Qb   = (u16*)(ws + 17301504);      // [48][2048][64]  (pre-scaled)
  u16* Kb   = (u16*)(ws + 29884416);      // [48][2048][64]
  u16* Vb   = (u16*)(ws + 42467328);      // [48][64][2048]  (transposed)
  u16* AOb  = (u16*)(ws + 55050240);      // [8192][768]

  convert_x<<<6144, 256, 0, stream>>>(x, xb);
  convert_w<<<2304, 256, 0, stream>>>(wq, wk, wv, wo, wqkv, wob);

  gemm_bt<0><<<64 * 18, 256, 0, stream>>>(xb, wqkv, Qb, Kb, Vb, nullptr);
  attn_kernel<<<48 * 16, 512, 0, stream>>>(Qb, Kb, Vb, AOb);
  gemm_bt<1><<<64 * 6, 256, 0, stream>>>(AOb, wob, nullptr, nullptr, nullptr, out);
}

// Round 15
// 137.195 us; speedup vs baseline: 1.1654x; 1.1654x over previous
//
#include <hip/hip_runtime.h>
#include <stdint.h>

typedef unsigned short u16;
typedef __attribute__((ext_vector_type(8))) short short8;
typedef __attribute__((ext_vector_type(4))) short s16x4;
typedef __attribute__((ext_vector_type(4))) float f32x4;
typedef __attribute__((ext_vector_type(2))) unsigned uint2v;

#define MFMA16(a, b, c) __builtin_amdgcn_mfma_f32_16x16x32_bf16(a, b, c, 0, 0, 0)

// PV uses K=16 bf16 MFMA: B-operand k-layout (kg*4+i) matches swapped-QK P layout.
#if __has_builtin(__builtin_amdgcn_mfma_f32_16x16x16bf16_1k)
__device__ __forceinline__ f32x4 pv_mfma(s16x4 a, s16x4 b, f32x4 c) {
  return __builtin_amdgcn_mfma_f32_16x16x16bf16_1k(a, b, c, 0, 0, 0);
}
#else
__device__ __forceinline__ f32x4 pv_mfma(s16x4 a, s16x4 b, f32x4 c) {
  asm volatile("v_mfma_f32_16x16x16_bf16 %0, %1, %2, %0" : "+v"(c) : "v"(a), "v"(b));
  return c;
}
#endif

__device__ __forceinline__ void async16(void* lds, const void* g) {
  __builtin_amdgcn_global_load_lds(
      (const __attribute__((address_space(1))) void*)g,
      (__attribute__((address_space(3))) void*)lds, 16, 0, 0);
}

__device__ __forceinline__ u16 f2bf(float f) {
  unsigned u = __float_as_uint(f);
  u += 0x7FFF + ((u >> 16) & 1);
  return (u16)(u >> 16);
}

__device__ __forceinline__ unsigned cvtpk(float lo, float hi) {
  unsigned r;
  asm("v_cvt_pk_bf16_f32 %0, %1, %2" : "=v"(r) : "v"(lo), "v"(hi));
  return r;
}

// Q is pre-scaled by 1/sqrt(dh) * log2(e) so softmax runs in exp2 domain.
#define QSCALE 0.18033688011112042f
// Mask sentinel: exp2f(MASKV) == 0 exactly; no arithmetic on it can overflow.
#define MASKV -30000.0f

// ---------------- fp32 -> bf16 conversion ----------------
__global__ void convert_x(const float* __restrict__ src, u16* __restrict__ dst) {
  int i = blockIdx.x * 256 + threadIdx.x;
  float4 v = ((const float4*)src)[i];
  unsigned lo = (unsigned)f2bf(v.x) | ((unsigned)f2bf(v.y) << 16);
  unsigned hi = (unsigned)f2bf(v.z) | ((unsigned)f2bf(v.w) << 16);
  ((uint2*)dst)[i] = make_uint2(lo, hi);
}

__global__ void convert_w(const float* __restrict__ wq, const float* __restrict__ wk,
                          const float* __restrict__ wv, const float* __restrict__ wo,
                          u16* __restrict__ wqkv, u16* __restrict__ wob) {
  int i = blockIdx.x * 256 + threadIdx.x;   // [0, 589824)
  int wsel = i / 147456;
  int r = i - wsel * 147456;
  const float* s = (wsel == 0) ? wq : (wsel == 1) ? wk : (wsel == 2) ? wv : wo;
  float4 v = ((const float4*)s)[r];
  unsigned lo = (unsigned)f2bf(v.x) | ((unsigned)f2bf(v.y) << 16);
  unsigned hi = (unsigned)f2bf(v.z) | ((unsigned)f2bf(v.w) << 16);
  uint2 w = make_uint2(lo, hi);
  if (wsel < 3) ((uint2*)wqkv)[wsel * 147456 + r] = w;
  else ((uint2*)wob)[r] = w;
}

// ---------------- GEMM: C[m,n] = sum_k A[m,k] * Bw[n,k]  (both bf16, K=768) ----
// 128x128 tile, BK=32, double-buffered LDS with global_load_lds prefetch.
// SWP is COMPILE-TIME (R14 lesson: runtime `swp` branch in the K-loop kept both
// MFMA orientations live -> VGPR 80->108, occupancy 24.6->16.5%, net regression).
//  - SWP=true  (Q/K blocks, MODE 1): mfma(W,X) -> lane holds 4 consecutive d/c
//    -> 8B bf16-pair / 16B float4 coalesced stores.
//  - SWP=false (V blocks): mfma(X,W) -> lane holds 4 consecutive s -> 8B stores
//    into V^T. bnOff shifts bn so Q/K and V run as separate instantiations.
template <int MODE, bool SWP>
__global__ __launch_bounds__(256) void gemm_bt(const u16* __restrict__ A,
                                               const u16* __restrict__ Bw,
                                               u16* __restrict__ Qb, u16* __restrict__ Kb,
                                               u16* __restrict__ Vb, float* __restrict__ Out,
                                               int bnOff) {
  __shared__ __align__(16) u16 As[2][128 * 32];
  __shared__ __align__(16) u16 Bs[2][128 * 32];
  const int bm = blockIdx.x & 63;   // 64 M-tiles
  const int bn = (blockIdx.x >> 6) + bnOff;
  const int tid = threadIdx.x;
  const int wave = tid >> 6, lane = tid & 63;
  const int arow = lane & 15, kg = lane >> 4;
  const int wr = wave >> 1, wc = wave & 1;

  const int o = tid * 16;
  const int rowS = o >> 6;     // 64B rows (BK=32 bf16)
  const int cbS = o & 63;
  const char* gA0 = (const char*)A + (size_t)(bm * 128 + rowS) * 1536 + cbS;
  const char* gA1 = gA0 + (size_t)64 * 1536;
  const char* gB0 = (const char*)Bw + (size_t)(bn * 128 + rowS) * 1536 + cbS;
  const char* gB1 = gB0 + (size_t)64 * 1536;
  const int ldsw = wave * 1024;

  f32x4 acc[4][4];
#pragma unroll
  for (int m = 0; m < 4; ++m)
#pragma unroll
    for (int n = 0; n < 4; ++n) acc[m][n] = (f32x4)(0.0f);

  auto stage = [&](int buf) {
    async16((char*)As + buf * 8192 + ldsw,        gA0);
    async16((char*)As + buf * 8192 + ldsw + 4096, gA1);
    async16((char*)Bs + buf * 8192 + ldsw,        gB0);
    async16((char*)Bs + buf * 8192 + ldsw + 4096, gB1);
    gA0 += 64; gA1 += 64; gB0 += 64; gB1 += 64;
  };

  stage(0);
  asm volatile("s_waitcnt vmcnt(0)" ::: "memory");
  __builtin_amdgcn_s_barrier();

  int cur = 0;
  for (int kk = 0; kk < 24; ++kk) {
    if (kk + 1 < 24) stage(cur ^ 1);   // prefetch next K-step (hides under compute)

    const char* Ac = (const char*)As + cur * 8192;
    const char* Bc = (const char*)Bs + cur * 8192;
    short8 Xf[4], Wf[4];
#pragma unroll
    for (int m = 0; m < 4; ++m)
      Xf[m] = *(const short8*)(Ac + (wr * 64 + m * 16 + arow) * 64 + kg * 16);
#pragma unroll
    for (int n = 0; n < 4; ++n)
      Wf[n] = *(const short8*)(Bc + (wc * 64 + n * 16 + arow) * 64 + kg * 16);
#pragma unroll
    for (int m = 0; m < 4; ++m)
#pragma unroll
      for (int n = 0; n < 4; ++n) {
        if constexpr (SWP) acc[m][n] = MFMA16(Wf[n], Xf[m], acc[m][n]);
        else               acc[m][n] = MFMA16(Xf[m], Wf[n], acc[m][n]);
      }

    asm volatile("s_waitcnt vmcnt(0)" ::: "memory");
    __builtin_amdgcn_s_barrier();
    cur ^= 1;
  }

  if constexpr (MODE == 0) {
    const int b = bm >> 4;                         // batch (block-uniform)
    const int which = bn / 6;                      // 0=Q 1=K 2=V (block-uniform)
    const int cbase = bn * 128 - which * 768 + wc * 64;
    if constexpr (!SWP) {
      // V (normal orientation): lane holds 4 consecutive s -> 8B stores to V^T
      const int sb = (bm & 15) * 128 + wr * 64 + kg * 4;  // + m*16 + i -> s
#pragma unroll
      for (int n = 0; n < 4; ++n) {
        int hc = cbase + n * 16 + arow;
        size_t rowb = ((size_t)(b * 12 + (hc >> 6)) * 64 + (hc & 63)) * 2048;
#pragma unroll
        for (int m = 0; m < 4; ++m) {
          uint2v w;
          w.x = cvtpk(acc[m][n][0], acc[m][n][1]);
          w.y = cvtpk(acc[m][n][2], acc[m][n][3]);
          *(uint2v*)(Vb + rowb + sb + m * 16) = w;
        }
      }
    } else {
      // Q/K (swapped orientation): lane holds 4 consecutive d -> 8B stores
      u16* const dst = which ? Kb : Qb;
      const float sc = which ? 1.0f : QSCALE;
      const int s0 = (bm & 15) * 128 + wr * 64 + arow;    // + m*16 -> s
#pragma unroll
      for (int n = 0; n < 4; ++n) {
        int hc0 = cbase + n * 16 + kg * 4;                // 4 consecutive d via i
        size_t hb = ((size_t)(b * 12 + (hc0 >> 6)) * 2048) * 64 + (hc0 & 63);
#pragma unroll
        for (int m = 0; m < 4; ++m) {
          uint2v w;
          w.x = cvtpk(acc[m][n][0] * sc, acc[m][n][1] * sc);
          w.y = cvtpk(acc[m][n][2] * sc, acc[m][n][3] * sc);
          *(uint2v*)(dst + hb + (size_t)(s0 + m * 16) * 64) = w;
        }
      }
    }
  } else {
    // MODE 1 (swapped orientation): lane holds 4 consecutive c -> float4 stores
    const int rbase = bm * 128 + wr * 64 + arow;          // + m*16 -> row
    const int c0 = bn * 128 + wc * 64 + kg * 4;           // + n*16 -> col
#pragma unroll
    for (int m = 0; m < 4; ++m)
#pragma unroll
      for (int n = 0; n < 4; ++n) {
        float4 st = make_float4(acc[m][n][0], acc[m][n][1], acc[m][n][2], acc[m][n][3]);
        *(float4*)(Out + (size_t)(rbase + m * 16) * 768 + c0 + n * 16) = st;
      }
  }
}

// ---------------- causal flash attention (swapped QK^T, ADJACENT pairing, ----
// ---------------- STATIC softmax) — byte-identical to the R13 passing build --
__global__ __launch_bounds__(512, 4) void attn_kernel(const u16* __restrict__ Qb,
                                                      const u16* __restrict__ Kb,
                                                      const u16* __restrict__ Vb,  // [bh][64][2048]
                                                      u16* __restrict__ AOb) {
  __shared__ __align__(16) u16 Ks[2][64 * 64];   // K tiles, XOR-swizzled 128B rows
  __shared__ __align__(16) u16 Vt[2][64 * 64];   // V^T tiles [d][k], XOR-swizzled

  const int bid = blockIdx.x;
  const int t = 15 - (bid / 48);     // pair index, heavy-first (t=15: 32 steps)
  const int bh = bid % 48;
  const int tid = threadIdx.x, wave = tid >> 6, lane = tid & 63;
  const int wgrp = wave >> 2, wq = wave & 3;
  const int arow = lane & 15, kg = lane >> 4;
  const int qt = wgrp ? (2 * t) : (2 * t + 1);   // group 0: odd (long); group 1: even
  const size_t hbase = (size_t)bh * (2048 * 64);
  const u16* Qh = Qb + hbase;
  const int q0 = qt * 64 + wq * 16;

  short8 qf[2];
#pragma unroll
  for (int ks = 0; ks < 2; ++ks)
    qf[ks] = *(const short8*)(Qh + (size_t)(q0 + arow) * 64 + ks * 32 + kg * 8);

  f32x4 o_acc[4];
#pragma unroll
  for (int n = 0; n < 4; ++n) o_acc[n] = (f32x4)(0.0f);
  float lsum = 0.0f;   // lane-local; reduced across kg groups in the epilogue

  const int o0 = tid * 16;                  // [0, 8192)
  const int r0 = o0 >> 7, cb0 = o0 & 127;   // row 0..63, byte-in-row
  const int sw0 = cb0 ^ (((r0 ^ (r0 >> 3)) & 7) << 4);
  char* const KsB = (char*)Ks;
  char* const VtB = (char*)Vt;
  const int ldsw = wave << 10;              // wave-uniform base offset

  const char* gK = (const char*)(Kb + hbase) + r0 * 128 + sw0;
  const char* gV = (const char*)(Vb + hbase) + (size_t)r0 * 4096 + sw0;

  const int nt = 2 * t + 2;   // k-steps for this pair (long tile's range)

  auto stage = [&](int buf) {
    async16(KsB + buf * 8192 + ldsw, gK);
    async16(VtB + buf * 8192 + ldsw, gV);
    gK += 8192;   // next K tile: 64 rows * 128B
    gV += 128;    // next V^T tile: 64 columns * 2B
  };

  const int rel = wq * 16 + arow - kg * 4;   // diag mask helper (q - kbase - kg*4)

  stage(0);
  __syncthreads();

  int cur = 0;
  for (int kt = 0; kt < nt; ++kt) {
    if (kt + 1 < nt) stage(cur ^ 1);   // prefetch next tile; lands during compute

    if (kt <= qt) {                    // wave-uniform; group 1 idles ONLY at kt=nt-1
      const char* Kc = KsB + cur * 8192;
      const char* Vc = VtB + cur * 8192;

      f32x4 s_acc[4];
#pragma unroll
      for (int cg = 0; cg < 4; ++cg) s_acc[cg] = (f32x4)(0.0f);
#pragma unroll
      for (int cg = 0; cg < 4; ++cg) {
        int krow = cg * 16 + arow;
        int fsw = ((krow ^ (krow >> 3)) & 7) << 4;
#pragma unroll
        for (int ks = 0; ks < 2; ++ks) {
          short8 kf = *(const short8*)(Kc + (krow << 7) + ((ks * 64 + kg * 16) ^ fsw));
          s_acc[cg] = MFMA16(kf, qf[ks], s_acc[cg]);
        }
      }

      if (kt == qt) {
#pragma unroll
        for (int cg = 0; cg < 4; ++cg)
#pragma unroll
          for (int i = 0; i < 4; ++i)
            s_acc[cg][i] = (cg * 16 + i > rel) ? MASKV : s_acc[cg][i];
      }

      // static softmax: P = exp2(s) direct; lane-local l accumulation
      s16x4 pb[4];
#pragma unroll
      for (int cg = 0; cg < 4; ++cg) {
        float e0 = exp2f(s_acc[cg][0]);
        float e1 = exp2f(s_acc[cg][1]);
        float e2 = exp2f(s_acc[cg][2]);
        float e3 = exp2f(s_acc[cg][3]);
        lsum += e0 + e1 + e2 + e3;
        uint2v w;
        w.x = cvtpk(e0, e1);
        w.y = cvtpk(e2, e3);
        pb[cg] = __builtin_bit_cast(s16x4, w);
      }

#pragma unroll
      for (int n = 0; n < 4; ++n) {
        int vrow = n * 16 + arow;
        int f2 = ((vrow ^ (vrow >> 3)) & 7) << 4;
        const char* vb0 = Vc + (vrow << 7);
#pragma unroll
        for (int cg = 0; cg < 4; ++cg) {
          s16x4 va = *(const s16x4*)(vb0 + ((cg * 32 + kg * 8) ^ f2));
          o_acc[n] = pv_mfma(va, pb[cg], o_acc[n]);
        }
      }
    }

    __syncthreads();   // drains vmcnt+lgkm; next tile ready, buffer reads done
    cur ^= 1;
  }

  lsum += __shfl_xor(lsum, 16);
  lsum += __shfl_xor(lsum, 32);
  const int b = bh / 12, h = bh - b * 12;
  float rinv = 1.0f / lsum;   // lsum > 0: diagonal p = exp2(finite) > 0
  size_t obase = ((size_t)b * 2048 + q0 + arow) * 768 + h * 64 + kg * 4;
#pragma unroll
  for (int n = 0; n < 4; ++n) {
#pragma unroll
    for (int t2 = 0; t2 < 2; ++t2) {
      unsigned w = cvtpk(o_acc[n][2 * t2] * rinv, o_acc[n][2 * t2 + 1] * rinv);
      *(unsigned*)(&AOb[obase + n * 16 + 2 * t2]) = w;
    }
  }
}

// ---------------- launch ----------------
extern "C" void kernel_launch(void* const* d_in, const int* in_sizes, int n_in,
                              void* d_out, int out_size, void* d_ws, size_t ws_size,
                              hipStream_t stream) {
  const float* x = (const float*)d_in[0];
  const float* wq = (const float*)d_in[1];
  const float* wk = (const float*)d_in[2];
  const float* wv = (const float*)d_in[3];
  const float* wo = (const float*)d_in[4];
  float* out = (float*)d_out;

  char* ws = (char*)d_ws;
  u16* xb   = (u16*)(ws);                 // [8192][768]
  u16* wqkv = (u16*)(ws + 12582912);      // [2304][768] rows: wq, wk, wv
  u16* wob  = (u16*)(ws + 16121856);      // [768][768]
  u16* Qb   = (u16*)(ws + 17301504);      // [48][2048][64]  (pre-scaled)
  u16* Kb   = (u16*)(ws + 29884416);      // [48][2048][64]
  u16* Vb   = (u16*)(ws + 42467328);      // [48][64][2048]  (transposed)
  u16* AOb  = (u16*)(ws + 55050240);      // [8192][768]

  convert_x<<<6144, 256, 0, stream>>>(x, xb);
  convert_w<<<2304, 256, 0, stream>>>(wq, wk, wv, wo, wqkv, wob);

  gemm_bt<0, true><<<64 * 12, 256, 0, stream>>>(xb, wqkv, Qb, Kb, Vb, nullptr, 0);   // Q,K
  gemm_bt<0, false><<<64 * 6, 256, 0, stream>>>(xb, wqkv, Qb, Kb, Vb, nullptr, 12);  // V
  attn_kernel<<<48 * 16, 512, 0, stream>>>(Qb, Kb, Vb, AOb);
  gemm_bt<1, true><<<64 * 6, 256, 0, stream>>>(AOb, wob, nullptr, nullptr, nullptr, out, 0);
}

// Round 16
// 131.973 us; speedup vs baseline: 1.2115x; 1.0396x over previous
//
#include <hip/hip_runtime.h>
#include <stdint.h>

typedef unsigned short u16;
typedef __attribute__((ext_vector_type(8))) short short8;
typedef __attribute__((ext_vector_type(4))) short s16x4;
typedef __attribute__((ext_vector_type(4))) float f32x4;
typedef __attribute__((ext_vector_type(2))) unsigned uint2v;

#define MFMA16(a, b, c) __builtin_amdgcn_mfma_f32_16x16x32_bf16(a, b, c, 0, 0, 0)

// PV uses K=16 bf16 MFMA: B-operand k-layout (kg*4+i) matches swapped-QK P layout.
#if __has_builtin(__builtin_amdgcn_mfma_f32_16x16x16bf16_1k)
__device__ __forceinline__ f32x4 pv_mfma(s16x4 a, s16x4 b, f32x4 c) {
  return __builtin_amdgcn_mfma_f32_16x16x16bf16_1k(a, b, c, 0, 0, 0);
}
#else
__device__ __forceinline__ f32x4 pv_mfma(s16x4 a, s16x4 b, f32x4 c) {
  asm volatile("v_mfma_f32_16x16x16_bf16 %0, %1, %2, %0" : "+v"(c) : "v"(a), "v"(b));
  return c;
}
#endif

__device__ __forceinline__ void async16(void* lds, const void* g) {
  __builtin_amdgcn_global_load_lds(
      (const __attribute__((address_space(1))) void*)g,
      (__attribute__((address_space(3))) void*)lds, 16, 0, 0);
}

__device__ __forceinline__ u16 f2bf(float f) {
  unsigned u = __float_as_uint(f);
  u += 0x7FFF + ((u >> 16) & 1);
  return (u16)(u >> 16);
}

__device__ __forceinline__ unsigned cvtpk(float lo, float hi) {
  unsigned r;
  asm("v_cvt_pk_bf16_f32 %0, %1, %2" : "=v"(r) : "v"(lo), "v"(hi));
  return r;
}

// Q is pre-scaled by 1/sqrt(dh) * log2(e) so softmax runs in exp2 domain.
#define QSCALE 0.18033688011112042f
// Mask sentinel: exp2f(MASKV) == 0 exactly; no arithmetic on it can overflow.
#define MASKV -30000.0f
// attn LDS swizzle: (r&7)<<4. Rows r/r+8 alias to the same 16B slot but their
// addresses differ by 1024B -> same banks -> 2-way aliasing (free, m136).
// Key property: (cg*16+arow)&7 == arow&7 == (n*16+arow)&7, so the XOR term is
// cg/n-INDEPENDENT -> all LDS read addresses decompose into a few hoistable
// lane-VGPRs + compile-time immediates (R15's cg-dependent swizzle forced
// per-iteration address recompute: ~70 VALU/lane/step, half the VALU budget).
#define SWZ(r) (((r) & 7) << 4)

// ---------------- fp32 -> bf16 conversion ----------------
__global__ void convert_x(const float* __restrict__ src, u16* __restrict__ dst) {
  int i = blockIdx.x * 256 + threadIdx.x;
  float4 v = ((const float4*)src)[i];
  unsigned lo = (unsigned)f2bf(v.x) | ((unsigned)f2bf(v.y) << 16);
  unsigned hi = (unsigned)f2bf(v.z) | ((unsigned)f2bf(v.w) << 16);
  ((uint2*)dst)[i] = make_uint2(lo, hi);
}

__global__ void convert_w(const float* __restrict__ wq, const float* __restrict__ wk,
                          const float* __restrict__ wv, const float* __restrict__ wo,
                          u16* __restrict__ wqkv, u16* __restrict__ wob) {
  int i = blockIdx.x * 256 + threadIdx.x;   // [0, 589824)
  int wsel = i / 147456;
  int r = i - wsel * 147456;
  const float* s = (wsel == 0) ? wq : (wsel == 1) ? wk : (wsel == 2) ? wv : wo;
  float4 v = ((const float4*)s)[r];
  unsigned lo = (unsigned)f2bf(v.x) | ((unsigned)f2bf(v.y) << 16);
  unsigned hi = (unsigned)f2bf(v.z) | ((unsigned)f2bf(v.w) << 16);
  uint2 w = make_uint2(lo, hi);
  if (wsel < 3) ((uint2*)wqkv)[wsel * 147456 + r] = w;
  else ((uint2*)wob)[r] = w;
}

// ---------------- GEMM: C[m,n] = sum_k A[m,k] * Bw[n,k]  (both bf16, K=768) ----
// 128x128 tile, BK=32, double-buffered LDS with global_load_lds prefetch.
// SWP is COMPILE-TIME (R14 lesson: runtime branch kept both MFMA orientations
// live -> VGPR 108, occupancy 16.5%). Byte-identical to the R15 passing build.
template <int MODE, bool SWP>
__global__ __launch_bounds__(256) void gemm_bt(const u16* __restrict__ A,
                                               const u16* __restrict__ Bw,
                                               u16* __restrict__ Qb, u16* __restrict__ Kb,
                                               u16* __restrict__ Vb, float* __restrict__ Out,
                                               int bnOff) {
  __shared__ __align__(16) u16 As[2][128 * 32];
  __shared__ __align__(16) u16 Bs[2][128 * 32];
  const int bm = blockIdx.x & 63;   // 64 M-tiles
  const int bn = (blockIdx.x >> 6) + bnOff;
  const int tid = threadIdx.x;
  const int wave = tid >> 6, lane = tid & 63;
  const int arow = lane & 15, kg = lane >> 4;
  const int wr = wave >> 1, wc = wave & 1;

  const int o = tid * 16;
  const int rowS = o >> 6;     // 64B rows (BK=32 bf16)
  const int cbS = o & 63;
  const char* gA0 = (const char*)A + (size_t)(bm * 128 + rowS) * 1536 + cbS;
  const char* gA1 = gA0 + (size_t)64 * 1536;
  const char* gB0 = (const char*)Bw + (size_t)(bn * 128 + rowS) * 1536 + cbS;
  const char* gB1 = gB0 + (size_t)64 * 1536;
  const int ldsw = wave * 1024;

  f32x4 acc[4][4];
#pragma unroll
  for (int m = 0; m < 4; ++m)
#pragma unroll
    for (int n = 0; n < 4; ++n) acc[m][n] = (f32x4)(0.0f);

  auto stage = [&](int buf) {
    async16((char*)As + buf * 8192 + ldsw,        gA0);
    async16((char*)As + buf * 8192 + ldsw + 4096, gA1);
    async16((char*)Bs + buf * 8192 + ldsw,        gB0);
    async16((char*)Bs + buf * 8192 + ldsw + 4096, gB1);
    gA0 += 64; gA1 += 64; gB0 += 64; gB1 += 64;
  };

  stage(0);
  asm volatile("s_waitcnt vmcnt(0)" ::: "memory");
  __builtin_amdgcn_s_barrier();

  int cur = 0;
  for (int kk = 0; kk < 24; ++kk) {
    if (kk + 1 < 24) stage(cur ^ 1);   // prefetch next K-step (hides under compute)

    const char* Ac = (const char*)As + cur * 8192;
    const char* Bc = (const char*)Bs + cur * 8192;
    short8 Xf[4], Wf[4];
#pragma unroll
    for (int m = 0; m < 4; ++m)
      Xf[m] = *(const short8*)(Ac + (wr * 64 + m * 16 + arow) * 64 + kg * 16);
#pragma unroll
    for (int n = 0; n < 4; ++n)
      Wf[n] = *(const short8*)(Bc + (wc * 64 + n * 16 + arow) * 64 + kg * 16);
#pragma unroll
    for (int m = 0; m < 4; ++m)
#pragma unroll
      for (int n = 0; n < 4; ++n) {
        if constexpr (SWP) acc[m][n] = MFMA16(Wf[n], Xf[m], acc[m][n]);
        else               acc[m][n] = MFMA16(Xf[m], Wf[n], acc[m][n]);
      }

    asm volatile("s_waitcnt vmcnt(0)" ::: "memory");
    __builtin_amdgcn_s_barrier();
    cur ^= 1;
  }

  if constexpr (MODE == 0) {
    const int b = bm >> 4;                         // batch (block-uniform)
    const int which = bn / 6;                      // 0=Q 1=K 2=V (block-uniform)
    const int cbase = bn * 128 - which * 768 + wc * 64;
    if constexpr (!SWP) {
      // V (normal orientation): lane holds 4 consecutive s -> 8B stores to V^T
      const int sb = (bm & 15) * 128 + wr * 64 + kg * 4;  // + m*16 + i -> s
#pragma unroll
      for (int n = 0; n < 4; ++n) {
        int hc = cbase + n * 16 + arow;
        size_t rowb = ((size_t)(b * 12 + (hc >> 6)) * 64 + (hc & 63)) * 2048;
#pragma unroll
        for (int m = 0; m < 4; ++m) {
          uint2v w;
          w.x = cvtpk(acc[m][n][0], acc[m][n][1]);
          w.y = cvtpk(acc[m][n][2], acc[m][n][3]);
          *(uint2v*)(Vb + rowb + sb + m * 16) = w;
        }
      }
    } else {
      // Q/K (swapped orientation): lane holds 4 consecutive d -> 8B stores
      u16* const dst = which ? Kb : Qb;
      const float sc = which ? 1.0f : QSCALE;
      const int s0 = (bm & 15) * 128 + wr * 64 + arow;    // + m*16 -> s
#pragma unroll
      for (int n = 0; n < 4; ++n) {
        int hc0 = cbase + n * 16 + kg * 4;                // 4 consecutive d via i
        size_t hb = ((size_t)(b * 12 + (hc0 >> 6)) * 2048) * 64 + (hc0 & 63);
#pragma unroll
        for (int m = 0; m < 4; ++m) {
          uint2v w;
          w.x = cvtpk(acc[m][n][0] * sc, acc[m][n][1] * sc);
          w.y = cvtpk(acc[m][n][2] * sc, acc[m][n][3] * sc);
          *(uint2v*)(dst + hb + (size_t)(s0 + m * 16) * 64) = w;
        }
      }
    }
  } else {
    // MODE 1 (swapped orientation): lane holds 4 consecutive c -> float4 stores
    const int rbase = bm * 128 + wr * 64 + arow;          // + m*16 -> row
    const int c0 = bn * 128 + wc * 64 + kg * 4;           // + n*16 -> col
#pragma unroll
    for (int m = 0; m < 4; ++m)
#pragma unroll
      for (int n = 0; n < 4; ++n) {
        float4 st = make_float4(acc[m][n][0], acc[m][n][1], acc[m][n][2], acc[m][n][3]);
        *(float4*)(Out + (size_t)(rbase + m * 16) * 768 + c0 + n * 16) = st;
      }
  }
}

// ---------------- causal flash attention (swapped QK^T, ADJACENT pairing, ----
// ---------------- STATIC softmax, unrolled-by-2 with hoistable addresses) ----
// grid: 48 head-batches * 16 pairs; block 512 = 2 wave-groups of 4 waves.
// Pair t: group 0 runs q-tile 2t+1 (nt=2t+2 steps, ALWAYS EVEN -> clean 2x
// unroll, no tail), group 1 runs q-tile 2t (skips only the final odd step).
// Unroll-by-2 makes buffer offsets literals (0/8192); SWZ(r)=(r&7)<<4 makes
// the XOR term cg/n-independent -> all kf/va LDS addresses are loop-invariant
// lane-VGPRs + immediates (zero per-step address VALU).
// Launch-bounds (512,4): proven-pass regime (cap32=spill, cap128=pass, cap256=NaN).
__global__ __launch_bounds__(512, 4) void attn_kernel(const u16* __restrict__ Qb,
                                                      const u16* __restrict__ Kb,
                                                      const u16* __restrict__ Vb,  // [bh][64][2048]
                                                      u16* __restrict__ AOb) {
  __shared__ __align__(16) u16 Ks[2][64 * 64];   // K tiles, SWZ-swizzled 128B rows
  __shared__ __align__(16) u16 Vt[2][64 * 64];   // V^T tiles [d][k], SWZ-swizzled

  const int bid = blockIdx.x;
  const int t = 15 - (bid / 48);     // pair index, heavy-first (t=15: 32 steps)
  const int bh = bid % 48;
  const int tid = threadIdx.x, wave = tid >> 6, lane = tid & 63;
  const int wgrp = wave >> 2, wq = wave & 3;
  const int arow = lane & 15, kg = lane >> 4;
  const int qt = wgrp ? (2 * t) : (2 * t + 1);   // group 0: odd (long); group 1: even
  const size_t hbase = (size_t)bh * (2048 * 64);
  const u16* Qh = Qb + hbase;
  const int q0 = qt * 64 + wq * 16;

  short8 qf[2];
#pragma unroll
  for (int ks = 0; ks < 2; ++ks)
    qf[ks] = *(const short8*)(Qh + (size_t)(q0 + arow) * 64 + ks * 32 + kg * 8);

  f32x4 o_acc[4];
#pragma unroll
  for (int n = 0; n < 4; ++n) o_acc[n] = (f32x4)(0.0f);
  float lsum = 0.0f;   // lane-local; reduced across kg groups in the epilogue

  // staging geometry: 512 threads cover rows 0..63 (one 8KB tile) per async16.
  // LDS dest linear; global source pre-swizzled with the SAME SWZ (G21).
  const int o0 = tid * 16;                  // [0, 8192)
  const int r0 = o0 >> 7, cb0 = o0 & 127;   // row 0..63, byte-in-row
  const int sw0 = cb0 ^ SWZ(r0);
  const int ldsw = wave << 10;              // wave-uniform base offset

  const char* gK = (const char*)(Kb + hbase) + r0 * 128 + sw0;
  const char* gV = (const char*)(Vb + hbase) + (size_t)r0 * 4096 + sw0;

  const int nt = 2 * t + 2;   // k-steps for this pair (long tile's range), EVEN

  auto stage = [&](int bufoff) {
    async16((char*)Ks + bufoff + ldsw, gK);
    async16((char*)Vt + bufoff + ldsw, gV);
    gK += 8192;   // next K tile: 64 rows * 128B
    gV += 128;    // next V^T tile: 64 columns * 2B
  };

  const int rel = wq * 16 + arow - kg * 4;   // diag mask helper (q - kbase - kg*4)

  // one tile-step of this wave's q-tile against buffer at compile-time bufoff
  auto body = [&](int ktv, int bufoff) {
    const char* Kc = (const char*)Ks + bufoff;
    const char* Vc = (const char*)Vt + bufoff;

    // swapped QK^T: mfma(A=K, B=Q) -> S[k][q]; lane: q=q0+arow, k=cg*16+kg*4+i
    f32x4 s_acc[4];
#pragma unroll
    for (int cg = 0; cg < 4; ++cg) s_acc[cg] = (f32x4)(0.0f);
#pragma unroll
    for (int cg = 0; cg < 4; ++cg) {
#pragma unroll
      for (int ks = 0; ks < 2; ++ks) {
        // addr = [(arow<<7) + ((ks*64+kg*16)^SWZ(arow))] (loop-invariant VGPR)
        //        + cg*2048 + bufoff (immediates)
        short8 kf = *(const short8*)(Kc + cg * 2048 + (arow << 7) +
                                     ((ks * 64 + kg * 16) ^ SWZ(arow)));
        s_acc[cg] = MFMA16(kf, qf[ks], s_acc[cg]);
      }
    }

    if (ktv == qt) {   // causal mask: this group's diagonal tile only
#pragma unroll
      for (int cg = 0; cg < 4; ++cg)
#pragma unroll
        for (int i = 0; i < 4; ++i)
          s_acc[cg][i] = (cg * 16 + i > rel) ? MASKV : s_acc[cg][i];
    }

    // static softmax: P = exp2(s) direct; lane-local l accumulation
    s16x4 pb[4];
#pragma unroll
    for (int cg = 0; cg < 4; ++cg) {
      float e0 = exp2f(s_acc[cg][0]);
      float e1 = exp2f(s_acc[cg][1]);
      float e2 = exp2f(s_acc[cg][2]);
      float e3 = exp2f(s_acc[cg][3]);
      lsum += e0 + e1 + e2 + e3;
      uint2v w;
      w.x = cvtpk(e0, e1);
      w.y = cvtpk(e2, e3);
      pb[cg] = __builtin_bit_cast(s16x4, w);
    }

    // PV: D[d][q] += V^T[d][k] * P[k][q] via 16x16x16 MFMA (K=16 per cg chunk)
#pragma unroll
    for (int n = 0; n < 4; ++n) {
#pragma unroll
      for (int cg = 0; cg < 4; ++cg) {
        // addr = [(arow<<7) + ((cg*32+kg*8)^SWZ(arow))] (loop-invariant VGPR)
        //        + n*2048 + bufoff (immediates)
        s16x4 va = *(const s16x4*)(Vc + n * 2048 + (arow << 7) +
                                   ((cg * 32 + kg * 8) ^ SWZ(arow)));
        o_acc[n] = pv_mfma(va, pb[cg], o_acc[n]);
      }
    }
  };

  // prologue: stage tile 0 into buf0, full drain
  stage(0);
  __syncthreads();

  for (int kt = 0; kt < nt; kt += 2) {
    // even step: compute buf0 (tile kt), prefetch tile kt+1 -> buf1
    stage(8192);                        // kt+1 <= nt-1 always inside the loop
    body(kt, 0);                        // both groups active on even steps
    __syncthreads();

    // odd step: compute buf1 (tile kt+1), prefetch tile kt+2 -> buf0
    if (kt + 2 < nt) stage(0);
    if (kt + 1 <= qt) body(kt + 1, 8192);   // group 1 skips only kt+1 == nt-1
    __syncthreads();
  }

  // epilogue: single l-reduction across kg groups, normalize, store bf16 pairs.
  lsum += __shfl_xor(lsum, 16);
  lsum += __shfl_xor(lsum, 32);
  const int b = bh / 12, h = bh - b * 12;
  float rinv = 1.0f / lsum;   // lsum > 0: diagonal p = exp2(finite) > 0
  size_t obase = ((size_t)b * 2048 + q0 + arow) * 768 + h * 64 + kg * 4;
#pragma unroll
  for (int n = 0; n < 4; ++n) {
#pragma unroll
    for (int t2 = 0; t2 < 2; ++t2) {
      unsigned w = cvtpk(o_acc[n][2 * t2] * rinv, o_acc[n][2 * t2 + 1] * rinv);
      *(unsigned*)(&AOb[obase + n * 16 + 2 * t2]) = w;
    }
  }
}

// ---------------- launch ----------------
extern "C" void kernel_launch(void* const* d_in, const int* in_sizes, int n_in,
                              void* d_out, int out_size, void* d_ws, size_t ws_size,
                              hipStream_t stream) {
  const float* x = (const float*)d_in[0];
  const float* wq = (const float*)d_in[1];
  const float* wk = (const float*)d_in[2];
  const float* wv = (const float*)d_in[3];
  const float* wo = (const float*)d_in[4];
  float* out = (float*)d_out;

  char* ws = (char*)d_ws;
  u16* xb   = (u16*)(ws);                 // [8192][768]
  u16* wqkv = (u16*)(ws + 12582912);      // [2304][768] rows: wq, wk, wv
  u16* wob  = (u16*)(ws + 16121856);      // [768][768]
  u16* Qb   = (u16*)(ws + 17301504);      // [48][2048][64]  (pre-scaled)
  u16* Kb   = (u16*)(ws + 29884416);      // [48][2048][64]
  u16* Vb   = (u16*)(ws + 42467328);      // [48][64][2048]  (transposed)
  u16* AOb  = (u16*)(ws + 55050240);      // [8192][768]

  convert_x<<<6144, 256, 0, stream>>>(x, xb);
  convert_w<<<2304, 256, 0, stream>>>(wq, wk, wv, wo, wqkv, wob);

  gemm_bt<0, true><<<64 * 12, 256, 0, stream>>>(xb, wqkv, Qb, Kb, Vb, nullptr, 0);   // Q,K
  gemm_bt<0, false><<<64 * 6, 256, 0, stream>>>(xb, wqkv, Qb, Kb, Vb, nullptr, 12);  // V
  attn_kernel<<<48 * 16, 512, 0, stream>>>(Qb, Kb, Vb, AOb);
  gemm_bt<1, true><<<64 * 6, 256, 0, stream>>>(AOb, wob, nullptr, nullptr, nullptr, out, 0);
}